// Round 12
// baseline (243.938 us; speedup 1.0000x reference)
//
#include <hip/hip_runtime.h>
#include <math.h>

// ---------------------------------------------------------------------------
// GCN_mamba_Net: fp16 MFMA; conv fused into Mamba2 scan; split-K8 chain.
// R12 = R11 + (split-K back to 8) + (k_conv fused into k_scan_m2_p1/k_gate).
// N=2048, F_IN=512, D_MODEL=D_INNER=256, NHEADS=32, HDIM=8, D_ST2=8,
// CONV_DIM=272, LAYERS=8, DT_RANK=16, N_STATE=16, NUM_CLASSES=40.
// ---------------------------------------------------------------------------

typedef _Float16 half8 __attribute__((ext_vector_type(8)));
typedef _Float16 half4v __attribute__((ext_vector_type(4)));
typedef float f32x4 __attribute__((ext_vector_type(4)));

__device__ __forceinline__ float softplus_fast(float x) {
    return fmaxf(x, 0.f) + __logf(1.f + __expf(-fabsf(x)));
}
__device__ __forceinline__ float silu_fast(float x) {
    return __fdividef(x, 1.f + __expf(-x));
}
// depthwise 4-tap conv + silu on xBC channel ch (Z col 256+ch), time t.
// dir=0 causal (taps t-3..t), dir=1 anti-causal (taps t..t+3, mirrored w).
__device__ __forceinline__ float conv_silu(
    const _Float16* __restrict__ Z16, const float* __restrict__ w,
    const float* __restrict__ b, int ch, int t, int dir)
{
    float acc = b[ch];
    #pragma unroll
    for (int k = 0; k < 4; ++k) {
        int tt = dir ? (t + 3 - k) : (t - 3 + k);
        if (tt >= 0 && tt < 2048)
            acc = fmaf(w[ch * 4 + k], (float)Z16[(size_t)tt * 560 + 256 + ch], acc);
    }
    return silu_fast(acc);
}

// ---------------------------------------------------------------------------
// Generic fp16 MFMA matmul: C[M,N] = A16[M,K](lda) @ BT16[Npad,K](ldb)^T.
// 256 thr = 4 waves; tile 128(m) x 64(n); BK=32; 16x16x32 f16 MFMA.
// grid (ceil(N/64), M/128, KSPLIT); kchunk = K/KSPLIT.
// EPI: 0 fp16 psum partial; 1 fp32 relu guarded; 2 fp16 gout; 3 fp32 all_out
//      remap + fp16 lastl; 4 fp16 dst16; 5 fp16 plain guarded.
// ---------------------------------------------------------------------------
template<int EPI>
__global__ __launch_bounds__(256) void mm16(
    const _Float16* __restrict__ A16, int lda,
    const _Float16* __restrict__ BT16, int ldb,
    float* __restrict__ dst, _Float16* __restrict__ dst16,
    const _Float16* __restrict__ aux16, _Float16* __restrict__ aux2_16,
    int N, int ldc, int kchunk)
{
    __shared__ _Float16 As[128][40];
    __shared__ _Float16 Bs[64][40];
    const int tid = threadIdx.x;
    const int col0 = blockIdx.x * 64;
    const int row0 = blockIdx.y * 128;
    const int kz = blockIdx.z;
    const int k0 = kz * kchunk;
    const int wave = tid >> 6, lane = tid & 63;
    f32x4 acc[2][4];
    #pragma unroll
    for (int i = 0; i < 2; ++i)
        #pragma unroll
        for (int j = 0; j < 4; ++j)
            acc[i][j] = (f32x4){0.f, 0.f, 0.f, 0.f};
    const int ar = tid >> 1, ac = (tid & 1) * 16;
    const int br = tid >> 2, bc = (tid & 3) * 8;
    const int lrow = lane & 15, kof = (lane >> 4) * 8;
    for (int ks = 0; ks < kchunk; ks += 32) {
        {
            const _Float16* src = A16 + (size_t)(row0 + ar) * lda + k0 + ks + ac;
            *reinterpret_cast<float4*>(&As[ar][ac])     = *reinterpret_cast<const float4*>(src);
            *reinterpret_cast<float4*>(&As[ar][ac + 8]) = *reinterpret_cast<const float4*>(src + 8);
        }
        {
            const _Float16* src = BT16 + (size_t)(col0 + br) * ldb + k0 + ks + bc;
            *reinterpret_cast<float4*>(&Bs[br][bc]) = *reinterpret_cast<const float4*>(src);
        }
        __syncthreads();
        half8 a[2], b[4];
        #pragma unroll
        for (int fr = 0; fr < 2; ++fr)
            a[fr] = *reinterpret_cast<const half8*>(&As[wave * 32 + fr * 16 + lrow][kof]);
        #pragma unroll
        for (int fc = 0; fc < 4; ++fc)
            b[fc] = *reinterpret_cast<const half8*>(&Bs[fc * 16 + lrow][kof]);
        #pragma unroll
        for (int fr = 0; fr < 2; ++fr)
            #pragma unroll
            for (int fc = 0; fc < 4; ++fc)
                acc[fr][fc] = __builtin_amdgcn_mfma_f32_16x16x32_f16(a[fr], b[fc], acc[fr][fc], 0, 0, 0);
        __syncthreads();
    }
    const int col = lane & 15, rbase = (lane >> 4) * 4;
    #pragma unroll
    for (int fr = 0; fr < 2; ++fr)
        #pragma unroll
        for (int fc = 0; fc < 4; ++fc) {
            int c = col0 + fc * 16 + col;
            #pragma unroll
            for (int i = 0; i < 4; ++i) {
                int m = row0 + wave * 32 + fr * 16 + rbase + i;
                float v = acc[fr][fc][i];
                if (EPI == 0) {
                    _Float16* P = dst16 + (size_t)kz * gridDim.y * 128 * 256;
                    P[(size_t)m * 256 + c] = (_Float16)v;
                } else if (EPI == 1) {
                    if (c < N) dst[(size_t)m * ldc + c] = fmaxf(v, 0.f);
                } else if (EPI == 2) {
                    dst16[(size_t)m * 256 + c] =
                        (_Float16)(fmaxf(v, 0.f) * 0.9f + 0.1f * (float)aux16[(size_t)m * 256 + c]);
                } else if (EPI == 3) {
                    int bb = m & 2047, ll = m >> 11;
                    dst[(size_t)((bb << 3) + ll) * 256 + c] = fmaxf(v, 0.f);
                    if (ll == 7) aux2_16[(size_t)bb * 256 + c] = (_Float16)v;
                } else if (EPI == 4) {
                    dst16[(size_t)m * 256 + c] = (_Float16)v;
                } else {
                    if (c < N) dst16[(size_t)m * ldc + c] = (_Float16)v;
                }
            }
        }
}

// xi = 0.95*sum(psum16[0..7]) + 0.05*xb16; half4-vectorized; xi16 + fT16^T.
__global__ __launch_bounds__(256) void k_combine16(
    const _Float16* __restrict__ psum16, const _Float16* __restrict__ xb16,
    _Float16* __restrict__ xi16, _Float16* __restrict__ fT16)
{
    int m0 = (blockIdx.x >> 3) * 32, n0 = (blockIdx.x & 7) * 32;
    int row = threadIdx.x >> 3;       // 0..31
    int c4  = (threadIdx.x & 7) * 4;  // 0,4,..,28
    __shared__ float T[32][33];
    size_t idx = (size_t)(m0 + row) * 256 + n0 + c4;
    float s[4] = {0.f, 0.f, 0.f, 0.f};
    #pragma unroll
    for (int q = 0; q < 8; ++q) {
        half4v pv = *reinterpret_cast<const half4v*>(&psum16[idx + (size_t)q * 524288]);
        s[0] += (float)pv[0]; s[1] += (float)pv[1];
        s[2] += (float)pv[2]; s[3] += (float)pv[3];
    }
    half4v xv = *reinterpret_cast<const half4v*>(&xb16[idx]);
    half4v ov;
    #pragma unroll
    for (int j = 0; j < 4; ++j) {
        float v = 0.95f * s[j] + 0.05f * (float)xv[j];
        ov[j] = (_Float16)v;
        T[row][c4 + j] = v;
    }
    *reinterpret_cast<half4v*>(&xi16[idx]) = ov;
    __syncthreads();
    int tx = threadIdx.x & 31, tg = threadIdx.x >> 5;
    #pragma unroll
    for (int j = 0; j < 4; ++j) {
        int n = tg * 4 + j;
        fT16[(size_t)(n0 + n) * 2048 + m0 + tx] = (_Float16)T[tx][n];
    }
}

// ---------------------------------------------------------------------------
// One-shot prep: x->fp16, adj->fp16, 5 transposed fp16 weights (zero-padded).
// ---------------------------------------------------------------------------
__global__ __launch_bounds__(256) void k_prep(
    const float* __restrict__ x, const float* __restrict__ adj,
    const float* __restrict__ lin1W, const float* __restrict__ inproj,
    const float* __restrict__ outprj, const float* __restrict__ xprojW,
    const float* __restrict__ boutW,
    _Float16* __restrict__ x16, _Float16* __restrict__ adj16,
    _Float16* __restrict__ lin1WT, _Float16* __restrict__ inprojT,
    _Float16* __restrict__ outprjT, _Float16* __restrict__ xprojT,
    _Float16* __restrict__ WT16)
{
    int b = blockIdx.x, tid = threadIdx.x;
    if (b < 5120) {
        const float* src = (b < 1024) ? x : adj;
        _Float16* o = (b < 1024) ? x16 : adj16;
        int lb = (b < 1024) ? b : b - 1024;
        int i = (lb * 256 + tid) * 4;
        float4 v = *reinterpret_cast<const float4*>(&src[i]);
        half4v h;
        h[0] = (_Float16)v.x; h[1] = (_Float16)v.y; h[2] = (_Float16)v.z; h[3] = (_Float16)v.w;
        *reinterpret_cast<half4v*>(&o[i]) = h;
    } else if (b < 5632) {         // lin1W [512][256] -> [256][512]
        int idx = (b - 5120) * 256 + tid;
        int n = idx >> 9, k = idx & 511;
        lin1WT[idx] = (_Float16)lin1W[(size_t)k * 256 + n];
    } else if (b < 6208) {         // inproj [256][560] -> [576][256] pad
        int idx = (b - 5632) * 256 + tid;
        int n = idx >> 8, k = idx & 255;
        inprojT[idx] = (n < 560) ? (_Float16)inproj[(size_t)k * 560 + n] : (_Float16)0.f;
    } else if (b < 6464) {         // outprj [256][256] -> [256][256]
        int idx = (b - 6208) * 256 + tid;
        int n = idx >> 8, k = idx & 255;
        outprjT[idx] = (_Float16)outprj[(size_t)k * 256 + n];
    } else if (b < 6528) {         // xprojW [256][48] -> [64][256] pad
        int idx = (b - 6464) * 256 + tid;
        int n = idx >> 8, k = idx & 255;
        xprojT[idx] = (n < 48) ? (_Float16)xprojW[(size_t)k * 48 + n] : (_Float16)0.f;
    } else {                       // boutW [256][256] -> [256][256]
        int idx = (b - 6528) * 256 + tid;
        int n = idx >> 8, k = idx & 255;
        WT16[idx] = (_Float16)boutW[(size_t)k * 256 + n];
    }
}

// xb = relu(bn1(X16)) -> fp16 feats16a[0] + fp16 transposed fT16
__global__ __launch_bounds__(256) void k_xb_t16(
    const _Float16* __restrict__ X16, const float* __restrict__ g, const float* __restrict__ b,
    _Float16* __restrict__ f16a, _Float16* __restrict__ fT16)
{
    const float sc = 0.99999500003749951f;  // 1/sqrt(1+1e-5)
    int m0 = (blockIdx.x >> 3) * 32, n0 = (blockIdx.x & 7) * 32;
    int tx = threadIdx.x & 31, tg = threadIdx.x >> 5;
    __shared__ float T[32][33];
    float gd = g[n0 + tx] * sc, bd = b[n0 + tx];
    #pragma unroll
    for (int i = 0; i < 4; ++i) {
        int m = tg * 4 + i;
        size_t idx = (size_t)(m0 + m) * 256 + n0 + tx;
        float v = fmaxf((float)X16[idx] * gd + bd, 0.f);
        f16a[idx] = (_Float16)v;
        T[m][tx] = v;
    }
    __syncthreads();
    #pragma unroll
    for (int j = 0; j < 4; ++j) {
        int n = tg * 4 + j;
        fT16[(size_t)(n0 + n) * 2048 + m0 + tx] = (_Float16)T[tx][n];
    }
}

// ---------------------------------------------------------------------------
// Chunk-parallel Mamba2 scan (32 chunks of 64); dt/dA AND conv inline.
// ---------------------------------------------------------------------------
__global__ __launch_bounds__(64) void k_scan_m2_p1(
    const _Float16* __restrict__ Z16, const float* __restrict__ dtbias, const float* __restrict__ A_log,
    const float* __restrict__ convw, const float* __restrict__ convb,
    const float* __restrict__ Dvec,
    float* __restrict__ yf, float* __restrict__ yr,
    float* __restrict__ Ptbuf,   // [2][2048][32]
    float* __restrict__ Acbuf,   // [64][32]
    float* __restrict__ Sloc)    // [64][32][64]
{
    int bid = blockIdx.x;        // 0..2047
    int c  = bid & 31;
    int hh = bid >> 5;           // dir*32+h
    int dir = hh >> 5, h = hh & 31;
    float* yp = dir ? yr : yf;
    int lane = threadIdx.x;
    int p = lane >> 3, n = lane & 7;
    float Dh = Dvec[h];
    __shared__ float dts[64];
    __shared__ float dAs[64];
    __shared__ float xhs[64][8];
    __shared__ float Ps[64][8];
    __shared__ float Bs[64][8];
    __shared__ float Cs[64][8];
    __shared__ float Ys[64][8];
    __shared__ float Pts[64];
    const int j0 = c * 64;
    {
        int j = j0 + lane;
        int t = dir ? (2047 - j) : j;
        float v = (float)Z16[(size_t)t * 560 + 528 + h] + dtbias[h];
        float dtv = softplus_fast(v);
        dts[lane] = dtv;
        dAs[lane] = __expf(-dtv * __expf(A_log[h]));
    }
    __syncthreads();
    for (int q = 0; q < 8; ++q) {
        int idx = q * 64 + lane;
        int i = idx >> 3, e = idx & 7;
        int j = j0 + i;
        int t = dir ? (2047 - j) : j;
        float xh = conv_silu(Z16, convw, convb, h * 8 + e, t, dir);
        xhs[i][e] = xh;
        Ps[i][e] = dts[i] * xh;
        Bs[i][e] = conv_silu(Z16, convw, convb, 256 + e, t, dir);
        Cs[i][e] = conv_silu(Z16, convw, convb, 264 + e, t, dir);
    }
    __syncthreads();
    float s = 0.f;
    float P = 1.f;
    for (int i = 0; i < 64; ++i) {
        float a = dAs[i];
        float u = Ps[i][p] * Bs[i][n];
        s = fmaf(a, s, u);
        P *= a;
        float yv = s * Cs[i][n];
        yv += __shfl_xor(yv, 1);
        yv += __shfl_xor(yv, 2);
        yv += __shfl_xor(yv, 4);
        if (n == 0) Ys[i][p] = yv;
        if (lane == 0) Pts[i] = P;
    }
    __syncthreads();
    for (int q = 0; q < 8; ++q) {
        int idx = q * 64 + lane;
        int i = idx >> 3, e = idx & 7;
        int j = j0 + i;
        int t = dir ? (2047 - j) : j;
        yp[(size_t)t * 256 + h * 8 + e] = Ys[i][e] + xhs[i][e] * Dh;
    }
    {
        int j = j0 + lane;
        Ptbuf[((size_t)dir * 2048 + j) * 32 + h] = Pts[lane];
    }
    if (lane == 0) Acbuf[hh * 32 + c] = P;
    Sloc[((size_t)hh * 32 + c) * 64 + lane] = s;
}

__global__ __launch_bounds__(64) void k_scan_m2_p2(
    const float* __restrict__ Acbuf, const float* __restrict__ Sloc,
    float* __restrict__ Sstart)
{
    int hh = blockIdx.x;
    int lane = threadIdx.x;
    float s = 0.f;
    for (int c = 0; c < 32; ++c) {
        Sstart[((size_t)hh * 32 + c) * 64 + lane] = s;
        float a = Acbuf[hh * 32 + c];
        s = fmaf(a, s, Sloc[((size_t)hh * 32 + c) * 64 + lane]);
    }
}

// gating + per-direction RMS norm; C recomputed via conv; emits fp16 gsum16.
__global__ __launch_bounds__(256) void k_gate(
    const _Float16* __restrict__ Z16, const float* __restrict__ yf, const float* __restrict__ yr,
    const float* __restrict__ convw, const float* __restrict__ convb,
    const float* __restrict__ Ptbuf, const float* __restrict__ Sstart,
    const float* __restrict__ nw, _Float16* __restrict__ gsum16)
{
    int t = blockIdx.x, d = threadIdx.x;
    int h = d >> 3, p = d & 7;
    __shared__ float Csh[2][8];
    if (d < 8)       Csh[0][d] = conv_silu(Z16, convw, convb, 264 + d, t, 0);
    else if (d < 16) Csh[1][d - 8] = conv_silu(Z16, convw, convb, 264 + (d - 8), t, 1);
    __syncthreads();
    int jf = t, jr = 2047 - t;
    int cf = jf >> 6, cr = jr >> 6;
    float Ptf = Ptbuf[((size_t)jf) * 32 + h];
    float Ptr = Ptbuf[((size_t)2048 + jr) * 32 + h];
    const float* ssf = &Sstart[(((size_t)h) * 32 + cf) * 64 + p * 8];
    const float* ssr = &Sstart[(((size_t)(32 + h)) * 32 + cr) * 64 + p * 8];
    float dotf = 0.f, dotr = 0.f;
    #pragma unroll
    for (int n2 = 0; n2 < 8; ++n2) {
        dotf = fmaf(ssf[n2], Csh[0][n2], dotf);
        dotr = fmaf(ssr[n2], Csh[1][n2], dotr);
    }
    float yfv = yf[(size_t)t * 256 + d] + Ptf * dotf;
    float yrv = yr[(size_t)t * 256 + d] + Ptr * dotr;
    float zv = (float)Z16[(size_t)t * 560 + d];
    float sz = silu_fast(zv);
    float gf = yfv * sz;
    float gr = yrv * sz;
    float vf = gf * gf, vr = gr * gr;
    for (int o = 32; o > 0; o >>= 1) { vf += __shfl_down(vf, o); vr += __shfl_down(vr, o); }
    __shared__ float sfa[4], sra[4];
    __shared__ float tot[2];
    int wid = d >> 6;
    if ((d & 63) == 0) { sfa[wid] = vf; sra[wid] = vr; }
    __syncthreads();
    if (d == 0) {
        tot[0] = sfa[0] + sfa[1] + sfa[2] + sfa[3];
        tot[1] = sra[0] + sra[1] + sra[2] + sra[3];
    }
    __syncthreads();
    float inf_ = rsqrtf(tot[0] / 256.f + 1e-5f);
    float inr_ = rsqrtf(tot[1] / 256.f + 1e-5f);
    gsum16[(size_t)t * 256 + d] = (_Float16)((gf * inf_ + gr * inr_) * nw[d]);
}

// GCN-mamba scan, fp16 in/out (in-place over feats16a).
__global__ __launch_bounds__(256) void k_scan_gcn(
    const float* __restrict__ xdbl,   // [16384][48]
    const float* __restrict__ dtW,    // [16][256]
    const float* __restrict__ A_log,  // [256][16]
    const float* __restrict__ Dv,     // [256]
    _Float16* __restrict__ f16io)     // [16384][256] feats in, y out
{
    int b = blockIdx.x, d = threadIdx.x;
    __shared__ float xrow[8][48];
    for (int j = d; j < 384; j += 256) {
        int l = j / 48, k = j % 48;
        xrow[l][k] = xdbl[(size_t)(l * 2048 + b) * 48 + k];
    }
    __syncthreads();
    float a[16];
    #pragma unroll
    for (int n = 0; n < 16; ++n) a[n] = -__expf(A_log[d * 16 + n]);
    float Dd = Dv[d];
    float s[16];
    #pragma unroll
    for (int n = 0; n < 16; ++n) s[n] = 0.f;
    for (int l = 0; l < 8; ++l) {
        float accd = 0.f;
        #pragma unroll
        for (int k = 0; k < 16; ++k) accd = fmaf(xrow[l][k], dtW[k * 256 + d], accd);
        float dl = softplus_fast(accd);
        size_t r = (size_t)(l * 2048 + b) * 256 + d;
        float xv = (float)f16io[r];
        float du = dl * xv;
        float y = 0.f;
        #pragma unroll
        for (int n = 0; n < 16; ++n) {
            float dAn = __expf(dl * a[n]);
            s[n] = fmaf(dAn, s[n], du * xrow[l][16 + n]);
            y = fmaf(s[n], xrow[l][32 + n], y);
        }
        f16io[r] = (_Float16)(y + xv * Dd);
    }
}

__global__ __launch_bounds__(256) void k_head(
    const _Float16* __restrict__ lastl16, const _Float16* __restrict__ X16,
    const _Float16* __restrict__ gout16,
    const float* __restrict__ g2, const float* __restrict__ b2, const float* __restrict__ W2,
    float* __restrict__ out1)
{
    int b = blockIdx.x, d = threadIdx.x;
    __shared__ float ov[256];
    __shared__ float yv[40];
    const float sc = 0.99999500003749951f;
    float v = ((float)lastl16[(size_t)b * 256 + d] + (float)X16[(size_t)b * 256 + d]) * 0.5f
              + (float)gout16[(size_t)b * 256 + d] * 0.5f;
    v = v * (g2[d] * sc) + b2[d];
    ov[d] = fmaxf(v, 0.f);
    __syncthreads();
    if (d < 40) {
        float acc = 0.f;
        for (int k = 0; k < 256; ++k) acc = fmaf(ov[k], W2[k * 40 + d], acc);
        yv[d] = acc;
    }
    __syncthreads();
    if (d < 40) {
        float m = -1e30f;
        for (int j = 0; j < 40; ++j) m = fmaxf(m, yv[j]);
        float se = 0.f;
        for (int j = 0; j < 40; ++j) se += expf(yv[j] - m);
        out1[(size_t)b * 40 + d] = yv[d] - m - logf(se);
    }
}

// ---------------------------------------------------------------------------
extern "C" void kernel_launch(void* const* d_in, const int* in_sizes, int n_in,
                              void* d_out, int out_size, void* d_ws, size_t ws_size,
                              hipStream_t stream)
{
    const float* x      = (const float*)d_in[0];
    const float* adj    = (const float*)d_in[1];
    const float* lin1W  = (const float*)d_in[2];
    const float* inproj = (const float*)d_in[3];
    const float* convw  = (const float*)d_in[4];
    const float* convb  = (const float*)d_in[5];
    const float* dtbias = (const float*)d_in[6];
    const float* m2Alog = (const float*)d_in[7];
    const float* m2D    = (const float*)d_in[8];
    const float* normw  = (const float*)d_in[9];
    const float* outprj = (const float*)d_in[10];
    const float* xprojW = (const float*)d_in[11];
    const float* dtprjW = (const float*)d_in[12];
    const float* bAlog  = (const float*)d_in[13];
    const float* bD     = (const float*)d_in[14];
    const float* boutW  = (const float*)d_in[15];
    const float* bn1g   = (const float*)d_in[16];
    const float* bn1b   = (const float*)d_in[17];
    const float* bn2g   = (const float*)d_in[18];
    const float* bn2b   = (const float*)d_in[19];
    const float* lin2W  = (const float*)d_in[20];
    float* out = (float*)d_out;
    float* ws  = (float*)d_ws;

    // fp32 buffers
    float* yf    = ws + 2916352;   // 2048x256
    float* yr    = ws + 3440640;   // 2048x256
    float* xdbl  = ws + 9207808;   // 16384x48
    // scan scratch (dead before chain; chain's psum16 overlays same region)
    float* scr    = ws + 10518528;
    float* Ptbuf  = scr;               // 131072
    float* Acbuf  = scr + 131072;      // 2048
    float* Sloc   = scr + 133120;      // 131072
    float* Sstart = scr + 264192;      // 131072
    // chain split-K fp16 psum (overlays scan scratch region, temporally disjoint)
    _Float16* psum16 = (_Float16*)(ws + 10518528);  // 8x2048x256 halves
    // fp16 buffers
    _Float16* Z16       = (_Float16*)(ws + 524288);    // 2048x560
    _Float16* gout16    = (_Float16*)(ws + 4489216);   // 2048x256
    _Float16* lastl16   = (_Float16*)(ws + 9994240);   // 2048x256
    _Float16* adj16h    = (_Float16*)(ws + 14712832);  // 2048x2048
    _Float16* fT16A     = (_Float16*)(ws + 16809984);  // 256x2048
    _Float16* WT16h     = (_Float16*)(ws + 17072128);  // boutW^T 256x256
    _Float16* x16       = (_Float16*)(ws + 17104896);  // 2048x512
    _Float16* lin1WT16  = (_Float16*)(ws + 17629184);  // 256x512
    _Float16* inprojT16 = (_Float16*)(ws + 17694720);  // 576x256
    _Float16* outprjT16 = (_Float16*)(ws + 17768448);  // 256x256
    _Float16* xprojT16  = (_Float16*)(ws + 17801216);  // 64x256
    _Float16* X16       = (_Float16*)(ws + 17809408);  // 2048x256
    _Float16* gsum16    = (_Float16*)(ws + 18071552);  // 2048x256
    _Float16* feats16a  = (_Float16*)(ws + 18333696);  // 16384x256
    (void)ws_size; (void)in_sizes; (void)n_in; (void)out_size;

    dim3 blk(256);
    // 1. one-shot conversions
    k_prep<<<dim3(6784), blk, 0, stream>>>(x, adj, lin1W, inproj, outprj, xprojW, boutW,
                                           x16, adj16h, lin1WT16, inprojT16, outprjT16,
                                           xprojT16, WT16h);
    // 2. X16 = x @ lin1_W  (fp16)
    mm16<4><<<dim3(4, 16, 1), blk, 0, stream>>>(x16, 512, lin1WT16, 512, nullptr, X16, nullptr, nullptr, 256, 256, 512);
    // 3. Z16 = X @ in_proj (fp16, N=560 guarded)
    mm16<5><<<dim3(9, 16, 1), blk, 0, stream>>>(X16, 256, inprojT16, 256, nullptr, Z16, nullptr, nullptr, 560, 560, 256);
    // 4. chunk-parallel bidirectional scan (conv + dt/dA inline)
    k_scan_m2_p1<<<dim3(2048), dim3(64), 0, stream>>>(Z16, dtbias, m2Alog, convw, convb,
                                                      m2D, yf, yr, Ptbuf, Acbuf, Sloc);
    k_scan_m2_p2<<<dim3(64), dim3(64), 0, stream>>>(Acbuf, Sloc, Sstart);
    // 5. gate + RMS -> gsum16 (C recomputed via conv)
    k_gate<<<dim3(2048), blk, 0, stream>>>(Z16, yf, yr, convw, convb, Ptbuf, Sstart, normw, gsum16);
    // 6. gout16 = relu(gsum@out_proj)*0.9 + 0.1*X16
    mm16<2><<<dim3(4, 16, 1), blk, 0, stream>>>(gsum16, 256, outprjT16, 256, nullptr, gout16, X16, nullptr, 256, 256, 256);
    // 7. feats16a[0] = xb (fp16 + fp16^T)
    k_xb_t16<<<dim3(512), blk, 0, stream>>>(X16, bn1g, bn1b, feats16a, fT16A);
    // 8. GCN chain via fp16 MFMA split-K=8 (fp16 psum) + vectorized combine
    for (int i = 1; i < 8; ++i) {
        mm16<0><<<dim3(4, 16, 8), blk, 0, stream>>>(adj16h, 2048, fT16A, 2048, nullptr, psum16, nullptr, nullptr, 256, 256, 256);
        k_combine16<<<dim3(512), blk, 0, stream>>>(psum16, feats16a,
                                                   feats16a + (size_t)i * 524288, fT16A);
    }
    // 9. xdbl = relu(feats @ xproj_W)  (fp32, N=48 guarded)
    mm16<1><<<dim3(1, 128, 1), blk, 0, stream>>>(feats16a, 256, xprojT16, 256, xdbl, nullptr, nullptr, nullptr, 48, 48, 256);
    // 10. GCN scan -> y (fp16 in-place)
    k_scan_gcn<<<dim3(2048), blk, 0, stream>>>(xdbl, dtprjW, bAlog, bD, feats16a);
    // 11. all_out = relu(y @ outproj_W) remap + lastl16
    mm16<3><<<dim3(4, 128, 1), blk, 0, stream>>>(feats16a, 256, WT16h, 256, out, nullptr, nullptr, lastl16, 256, 256, 256);
    // 12. head
    k_head<<<dim3(2048), blk, 0, stream>>>(lastl16, X16, gout16, bn2g, bn2b, lin2W, out + 4194304);
}

// Round 14
// 235.376 us; speedup vs baseline: 1.0364x; 1.0364x over previous
//
#include <hip/hip_runtime.h>
#include <math.h>

// ---------------------------------------------------------------------------
// GCN_mamba_Net: fp16 MFMA, split-K chain (fp16 psum) + combine kernels.
// R14 = R10 exactly (best measured: 235.9 us, absmax 0.03125).
// N=2048, F_IN=512, D_MODEL=D_INNER=256, NHEADS=32, HDIM=8, D_ST2=8,
// CONV_DIM=272, LAYERS=8, DT_RANK=16, N_STATE=16, NUM_CLASSES=40.
// ---------------------------------------------------------------------------

typedef _Float16 half8 __attribute__((ext_vector_type(8)));
typedef _Float16 half4v __attribute__((ext_vector_type(4)));
typedef float f32x4 __attribute__((ext_vector_type(4)));

__device__ __forceinline__ float softplus_fast(float x) {
    return fmaxf(x, 0.f) + __logf(1.f + __expf(-fabsf(x)));
}
__device__ __forceinline__ float silu_fast(float x) {
    return __fdividef(x, 1.f + __expf(-x));
}

// ---------------------------------------------------------------------------
// Generic fp16 MFMA matmul: C[M,N] = A16[M,K](lda) @ BT16[Npad,K](ldb)^T.
// 256 thr = 4 waves; tile 128(m) x 64(n); BK=32; 16x16x32 f16 MFMA.
// grid (ceil(N/64), M/128, KSPLIT); kchunk = K/KSPLIT.
// EPI: 0 fp16 psum partial [kz][M][256] (via dst16); 1 relu guarded;
//      2 gout relu*0.9+0.1*aux; 3 all_out remap + lastl(aux2);
//      4 fp32 + fp16 mirror; 5 plain guarded.
// ---------------------------------------------------------------------------
template<int EPI>
__global__ __launch_bounds__(256) void mm16(
    const _Float16* __restrict__ A16, int lda,
    const _Float16* __restrict__ BT16, int ldb,
    float* __restrict__ dst, _Float16* __restrict__ dst16,
    const float* __restrict__ aux, float* __restrict__ aux2,
    int N, int ldc, int kchunk)
{
    __shared__ _Float16 As[128][40];
    __shared__ _Float16 Bs[64][40];
    const int tid = threadIdx.x;
    const int col0 = blockIdx.x * 64;
    const int row0 = blockIdx.y * 128;
    const int kz = blockIdx.z;
    const int k0 = kz * kchunk;
    const int wave = tid >> 6, lane = tid & 63;
    f32x4 acc[2][4];
    #pragma unroll
    for (int i = 0; i < 2; ++i)
        #pragma unroll
        for (int j = 0; j < 4; ++j)
            acc[i][j] = (f32x4){0.f, 0.f, 0.f, 0.f};
    const int ar = tid >> 1, ac = (tid & 1) * 16;
    const int br = tid >> 2, bc = (tid & 3) * 8;
    const int lrow = lane & 15, kof = (lane >> 4) * 8;
    for (int ks = 0; ks < kchunk; ks += 32) {
        {
            const _Float16* src = A16 + (size_t)(row0 + ar) * lda + k0 + ks + ac;
            *reinterpret_cast<float4*>(&As[ar][ac])     = *reinterpret_cast<const float4*>(src);
            *reinterpret_cast<float4*>(&As[ar][ac + 8]) = *reinterpret_cast<const float4*>(src + 8);
        }
        {
            const _Float16* src = BT16 + (size_t)(col0 + br) * ldb + k0 + ks + bc;
            *reinterpret_cast<float4*>(&Bs[br][bc]) = *reinterpret_cast<const float4*>(src);
        }
        __syncthreads();
        half8 a[2], b[4];
        #pragma unroll
        for (int fr = 0; fr < 2; ++fr)
            a[fr] = *reinterpret_cast<const half8*>(&As[wave * 32 + fr * 16 + lrow][kof]);
        #pragma unroll
        for (int fc = 0; fc < 4; ++fc)
            b[fc] = *reinterpret_cast<const half8*>(&Bs[fc * 16 + lrow][kof]);
        #pragma unroll
        for (int fr = 0; fr < 2; ++fr)
            #pragma unroll
            for (int fc = 0; fc < 4; ++fc)
                acc[fr][fc] = __builtin_amdgcn_mfma_f32_16x16x32_f16(a[fr], b[fc], acc[fr][fc], 0, 0, 0);
        __syncthreads();
    }
    const int col = lane & 15, rbase = (lane >> 4) * 4;
    #pragma unroll
    for (int fr = 0; fr < 2; ++fr)
        #pragma unroll
        for (int fc = 0; fc < 4; ++fc) {
            int c = col0 + fc * 16 + col;
            #pragma unroll
            for (int i = 0; i < 4; ++i) {
                int m = row0 + wave * 32 + fr * 16 + rbase + i;
                float v = acc[fr][fc][i];
                if (EPI == 0) {
                    _Float16* P = dst16 + (size_t)kz * gridDim.y * 128 * 256;
                    P[(size_t)m * 256 + c] = (_Float16)v;
                } else if (EPI == 1) {
                    if (c < N) dst[(size_t)m * ldc + c] = fmaxf(v, 0.f);
                } else if (EPI == 2) {
                    dst[(size_t)m * 256 + c] = fmaxf(v, 0.f) * 0.9f + 0.1f * aux[(size_t)m * 256 + c];
                } else if (EPI == 3) {
                    int bb = m & 2047, ll = m >> 11;
                    dst[(size_t)((bb << 3) + ll) * 256 + c] = fmaxf(v, 0.f);
                    if (ll == 7) aux2[(size_t)bb * 256 + c] = v;
                } else if (EPI == 4) {
                    dst[(size_t)m * 256 + c] = v;
                    dst16[(size_t)m * 256 + c] = (_Float16)v;
                } else {
                    if (c < N) dst[(size_t)m * ldc + c] = v;
                }
            }
        }
}

// xi = 0.95*sum(psum16[0..7]) + 0.05*xb16; fp16 outputs: xi16 + fT16^T.
__global__ __launch_bounds__(256) void k_combine16(
    const _Float16* __restrict__ psum16, const _Float16* __restrict__ xb16,
    _Float16* __restrict__ xi16, _Float16* __restrict__ fT16)
{
    int m0 = (blockIdx.x >> 3) * 32, n0 = (blockIdx.x & 7) * 32;
    int tx = threadIdx.x & 31, tg = threadIdx.x >> 5;
    __shared__ float T[32][33];
    #pragma unroll
    for (int i = 0; i < 4; ++i) {
        int m = tg * 4 + i;
        size_t idx = (size_t)(m0 + m) * 256 + n0 + tx;
        float s = 0.f;
        #pragma unroll
        for (int q = 0; q < 8; ++q) s += (float)psum16[idx + (size_t)q * 524288];
        float v = 0.95f * s + 0.05f * (float)xb16[idx];
        xi16[idx] = (_Float16)v;
        T[m][tx] = v;
    }
    __syncthreads();
    #pragma unroll
    for (int j = 0; j < 4; ++j) {
        int n = tg * 4 + j;
        fT16[(size_t)(n0 + n) * 2048 + m0 + tx] = (_Float16)T[tx][n];
    }
}

// ---------------------------------------------------------------------------
// One-shot prep: x->fp16, adj->fp16, 5 transposed fp16 weights (zero-padded).
// ---------------------------------------------------------------------------
__global__ __launch_bounds__(256) void k_prep(
    const float* __restrict__ x, const float* __restrict__ adj,
    const float* __restrict__ lin1W, const float* __restrict__ inproj,
    const float* __restrict__ outprj, const float* __restrict__ xprojW,
    const float* __restrict__ boutW,
    _Float16* __restrict__ x16, _Float16* __restrict__ adj16,
    _Float16* __restrict__ lin1WT, _Float16* __restrict__ inprojT,
    _Float16* __restrict__ outprjT, _Float16* __restrict__ xprojT,
    _Float16* __restrict__ WT16)
{
    int b = blockIdx.x, tid = threadIdx.x;
    if (b < 5120) {
        const float* src = (b < 1024) ? x : adj;
        _Float16* o = (b < 1024) ? x16 : adj16;
        int lb = (b < 1024) ? b : b - 1024;
        int i = (lb * 256 + tid) * 4;
        float4 v = *reinterpret_cast<const float4*>(&src[i]);
        half4v h;
        h[0] = (_Float16)v.x; h[1] = (_Float16)v.y; h[2] = (_Float16)v.z; h[3] = (_Float16)v.w;
        *reinterpret_cast<half4v*>(&o[i]) = h;
    } else if (b < 5632) {         // lin1W [512][256] -> [256][512]
        int idx = (b - 5120) * 256 + tid;
        int n = idx >> 9, k = idx & 511;
        lin1WT[idx] = (_Float16)lin1W[(size_t)k * 256 + n];
    } else if (b < 6208) {         // inproj [256][560] -> [576][256] pad
        int idx = (b - 5632) * 256 + tid;
        int n = idx >> 8, k = idx & 255;
        inprojT[idx] = (n < 560) ? (_Float16)inproj[(size_t)k * 560 + n] : (_Float16)0.f;
    } else if (b < 6464) {         // outprj [256][256] -> [256][256]
        int idx = (b - 6208) * 256 + tid;
        int n = idx >> 8, k = idx & 255;
        outprjT[idx] = (_Float16)outprj[(size_t)k * 256 + n];
    } else if (b < 6528) {         // xprojW [256][48] -> [64][256] pad
        int idx = (b - 6464) * 256 + tid;
        int n = idx >> 8, k = idx & 255;
        xprojT[idx] = (n < 48) ? (_Float16)xprojW[(size_t)k * 48 + n] : (_Float16)0.f;
    } else {                       // boutW [256][256] -> [256][256]
        int idx = (b - 6528) * 256 + tid;
        int n = idx >> 8, k = idx & 255;
        WT16[idx] = (_Float16)boutW[(size_t)k * 256 + n];
    }
}

// xb = relu(bn1(X)) -> fp16 feats16a[0] + fp16 transposed fT16
__global__ __launch_bounds__(256) void k_xb_t16(
    const float* __restrict__ X, const float* __restrict__ g, const float* __restrict__ b,
    _Float16* __restrict__ f16a, _Float16* __restrict__ fT16)
{
    const float sc = 0.99999500003749951f;  // 1/sqrt(1+1e-5)
    int m0 = (blockIdx.x >> 3) * 32, n0 = (blockIdx.x & 7) * 32;
    int tx = threadIdx.x & 31, tg = threadIdx.x >> 5;
    __shared__ float T[32][33];
    float gd = g[n0 + tx] * sc, bd = b[n0 + tx];
    #pragma unroll
    for (int i = 0; i < 4; ++i) {
        int m = tg * 4 + i;
        size_t idx = (size_t)(m0 + m) * 256 + n0 + tx;
        float v = fmaxf(X[idx] * gd + bd, 0.f);
        f16a[idx] = (_Float16)v;
        T[m][tx] = v;
    }
    __syncthreads();
    #pragma unroll
    for (int j = 0; j < 4; ++j) {
        int n = tg * 4 + j;
        fT16[(size_t)(n0 + n) * 2048 + m0 + tx] = (_Float16)T[tx][n];
    }
}

__global__ __launch_bounds__(320) void k_conv(
    const float* __restrict__ Z, const float* __restrict__ w, const float* __restrict__ bconv,
    float* __restrict__ xhf, float* __restrict__ Bf, float* __restrict__ Cf,
    float* __restrict__ xhr, float* __restrict__ Br, float* __restrict__ Cr)
{
    int bx = blockIdx.x;               // 0..4095
    int dir = bx >> 11, t = bx & 2047;
    int c = threadIdx.x;
    if (c >= 272) return;
    float acc = bconv[c];
    #pragma unroll
    for (int k = 0; k < 4; ++k) {
        int tt = dir ? (t + 3 - k) : (t - 3 + k);
        if (tt >= 0 && tt < 2048) acc = fmaf(w[c * 4 + k], Z[(size_t)tt * 560 + 256 + c], acc);
    }
    float v = silu_fast(acc);
    float* xh = dir ? xhr : xhf;
    float* B  = dir ? Br  : Bf;
    float* C  = dir ? Cr  : Cf;
    if (c < 256)       xh[(size_t)t * 256 + c] = v;
    else if (c < 264)  B[(size_t)t * 8 + (c - 256)] = v;
    else               C[(size_t)t * 8 + (c - 264)] = v;
}

// ---------------------------------------------------------------------------
// Chunk-parallel Mamba2 scan (32 chunks of 64); dt/dA inline from Z.
// ---------------------------------------------------------------------------
__global__ __launch_bounds__(64) void k_scan_m2_p1(
    const float* __restrict__ Z, const float* __restrict__ dtbias, const float* __restrict__ A_log,
    const float* __restrict__ xhf, const float* __restrict__ Bf, const float* __restrict__ Cf,
    const float* __restrict__ xhr, const float* __restrict__ Br, const float* __restrict__ Cr,
    const float* __restrict__ Dvec,
    float* __restrict__ yf, float* __restrict__ yr,
    float* __restrict__ Ptbuf,   // [2][2048][32]
    float* __restrict__ Acbuf,   // [64][32]
    float* __restrict__ Sloc)    // [64][32][64]
{
    int bid = blockIdx.x;        // 0..2047
    int c  = bid & 31;
    int hh = bid >> 5;           // dir*32+h
    int dir = hh >> 5, h = hh & 31;
    const float* xhp = dir ? xhr : xhf;
    const float* Bp  = dir ? Br  : Bf;
    const float* Cp  = dir ? Cr  : Cf;
    float* yp        = dir ? yr  : yf;
    int lane = threadIdx.x;
    int p = lane >> 3, n = lane & 7;
    float Dh = Dvec[h];
    __shared__ float dts[64];
    __shared__ float dAs[64];
    __shared__ float Ps[64][8];
    __shared__ float Bs[64][8];
    __shared__ float Cs[64][8];
    __shared__ float Ys[64][8];
    __shared__ float Pts[64];
    const int j0 = c * 64;
    {
        int j = j0 + lane;
        int t = dir ? (2047 - j) : j;
        float v = Z[(size_t)t * 560 + 528 + h] + dtbias[h];
        float dtv = softplus_fast(v);
        dts[lane] = dtv;
        dAs[lane] = __expf(-dtv * __expf(A_log[h]));
    }
    __syncthreads();
    #pragma unroll
    for (int q = 0; q < 8; ++q) {
        int idx = q * 64 + lane;
        int i = idx >> 3, e = idx & 7;
        int j = j0 + i;
        int t = dir ? (2047 - j) : j;
        Ps[i][e] = dts[i] * xhp[(size_t)t * 256 + h * 8 + e];
        Bs[i][e] = Bp[(size_t)t * 8 + e];
        Cs[i][e] = Cp[(size_t)t * 8 + e];
    }
    __syncthreads();
    float s = 0.f;
    float P = 1.f;
    for (int i = 0; i < 64; ++i) {
        float a = dAs[i];
        float u = Ps[i][p] * Bs[i][n];
        s = fmaf(a, s, u);
        P *= a;
        float yv = s * Cs[i][n];
        yv += __shfl_xor(yv, 1);
        yv += __shfl_xor(yv, 2);
        yv += __shfl_xor(yv, 4);
        if (n == 0) Ys[i][p] = yv;
        if (lane == 0) Pts[i] = P;
    }
    __syncthreads();
    #pragma unroll
    for (int q = 0; q < 8; ++q) {
        int idx = q * 64 + lane;
        int i = idx >> 3, e = idx & 7;
        int j = j0 + i;
        int t = dir ? (2047 - j) : j;
        yp[(size_t)t * 256 + h * 8 + e] = Ys[i][e] + xhp[(size_t)t * 256 + h * 8 + e] * Dh;
    }
    {
        int j = j0 + lane;
        Ptbuf[((size_t)dir * 2048 + j) * 32 + h] = Pts[lane];
    }
    if (lane == 0) Acbuf[hh * 32 + c] = P;
    Sloc[((size_t)hh * 32 + c) * 64 + lane] = s;
}

__global__ __launch_bounds__(64) void k_scan_m2_p2(
    const float* __restrict__ Acbuf, const float* __restrict__ Sloc,
    float* __restrict__ Sstart)
{
    int hh = blockIdx.x;
    int lane = threadIdx.x;
    float s = 0.f;
    for (int c = 0; c < 32; ++c) {
        Sstart[((size_t)hh * 32 + c) * 64 + lane] = s;
        float a = Acbuf[hh * 32 + c];
        s = fmaf(a, s, Sloc[((size_t)hh * 32 + c) * 64 + lane]);
    }
}

// gating + per-direction RMS norm; emits fp16 gsum16 only.
__global__ __launch_bounds__(256) void k_gate(
    const float* __restrict__ Z, const float* __restrict__ yf, const float* __restrict__ yr,
    const float* __restrict__ Cf, const float* __restrict__ Cr,
    const float* __restrict__ Ptbuf, const float* __restrict__ Sstart,
    const float* __restrict__ nw, _Float16* __restrict__ gsum16)
{
    int t = blockIdx.x, d = threadIdx.x;
    int h = d >> 3, p = d & 7;
    __shared__ float Csh[2][8];
    if (d < 8)       Csh[0][d] = Cf[(size_t)t * 8 + d];
    else if (d < 16) Csh[1][d - 8] = Cr[(size_t)t * 8 + (d - 8)];
    __syncthreads();
    int jf = t, jr = 2047 - t;
    int cf = jf >> 6, cr = jr >> 6;
    float Ptf = Ptbuf[((size_t)jf) * 32 + h];
    float Ptr = Ptbuf[((size_t)2048 + jr) * 32 + h];
    const float* ssf = &Sstart[(((size_t)h) * 32 + cf) * 64 + p * 8];
    const float* ssr = &Sstart[(((size_t)(32 + h)) * 32 + cr) * 64 + p * 8];
    float dotf = 0.f, dotr = 0.f;
    #pragma unroll
    for (int n2 = 0; n2 < 8; ++n2) {
        dotf = fmaf(ssf[n2], Csh[0][n2], dotf);
        dotr = fmaf(ssr[n2], Csh[1][n2], dotr);
    }
    float yfv = yf[(size_t)t * 256 + d] + Ptf * dotf;
    float yrv = yr[(size_t)t * 256 + d] + Ptr * dotr;
    float zv = Z[(size_t)t * 560 + d];
    float sz = silu_fast(zv);
    float gf = yfv * sz;
    float gr = yrv * sz;
    float vf = gf * gf, vr = gr * gr;
    for (int o = 32; o > 0; o >>= 1) { vf += __shfl_down(vf, o); vr += __shfl_down(vr, o); }
    __shared__ float sfa[4], sra[4];
    __shared__ float tot[2];
    int wid = d >> 6;
    if ((d & 63) == 0) { sfa[wid] = vf; sra[wid] = vr; }
    __syncthreads();
    if (d == 0) {
        tot[0] = sfa[0] + sfa[1] + sfa[2] + sfa[3];
        tot[1] = sra[0] + sra[1] + sra[2] + sra[3];
    }
    __syncthreads();
    float inf_ = rsqrtf(tot[0] / 256.f + 1e-5f);
    float inr_ = rsqrtf(tot[1] / 256.f + 1e-5f);
    gsum16[(size_t)t * 256 + d] = (_Float16)((gf * inf_ + gr * inr_) * nw[d]);
}

// GCN-mamba scan, fp16 in/out (in-place over feats16a).
__global__ __launch_bounds__(256) void k_scan_gcn(
    const float* __restrict__ xdbl,   // [16384][48]
    const float* __restrict__ dtW,    // [16][256]
    const float* __restrict__ A_log,  // [256][16]
    const float* __restrict__ Dv,     // [256]
    _Float16* __restrict__ f16io)     // [16384][256] feats in, y out
{
    int b = blockIdx.x, d = threadIdx.x;
    __shared__ float xrow[8][48];
    for (int j = d; j < 384; j += 256) {
        int l = j / 48, k = j % 48;
        xrow[l][k] = xdbl[(size_t)(l * 2048 + b) * 48 + k];
    }
    __syncthreads();
    float a[16];
    #pragma unroll
    for (int n = 0; n < 16; ++n) a[n] = -__expf(A_log[d * 16 + n]);
    float Dd = Dv[d];
    float s[16];
    #pragma unroll
    for (int n = 0; n < 16; ++n) s[n] = 0.f;
    for (int l = 0; l < 8; ++l) {
        float accd = 0.f;
        #pragma unroll
        for (int k = 0; k < 16; ++k) accd = fmaf(xrow[l][k], dtW[k * 256 + d], accd);
        float dl = softplus_fast(accd);
        size_t r = (size_t)(l * 2048 + b) * 256 + d;
        float xv = (float)f16io[r];
        float du = dl * xv;
        float y = 0.f;
        #pragma unroll
        for (int n = 0; n < 16; ++n) {
            float dAn = __expf(dl * a[n]);
            s[n] = fmaf(dAn, s[n], du * xrow[l][16 + n]);
            y = fmaf(s[n], xrow[l][32 + n], y);
        }
        f16io[r] = (_Float16)(y + xv * Dd);
    }
}

__global__ __launch_bounds__(256) void k_head(
    const float* __restrict__ lastl, const float* __restrict__ X, const float* __restrict__ gout,
    const float* __restrict__ g2, const float* __restrict__ b2, const float* __restrict__ W2,
    float* __restrict__ out1)
{
    int b = blockIdx.x, d = threadIdx.x;
    __shared__ float ov[256];
    __shared__ float yv[40];
    const float sc = 0.99999500003749951f;
    float v = (lastl[(size_t)b * 256 + d] + X[(size_t)b * 256 + d]) * 0.5f
              + gout[(size_t)b * 256 + d] * 0.5f;
    v = v * (g2[d] * sc) + b2[d];
    ov[d] = fmaxf(v, 0.f);
    __syncthreads();
    if (d < 40) {
        float acc = 0.f;
        for (int k = 0; k < 256; ++k) acc = fmaf(ov[k], W2[k * 40 + d], acc);
        yv[d] = acc;
    }
    __syncthreads();
    if (d < 40) {
        float m = -1e30f;
        for (int j = 0; j < 40; ++j) m = fmaxf(m, yv[j]);
        float se = 0.f;
        for (int j = 0; j < 40; ++j) se += expf(yv[j] - m);
        out1[(size_t)b * 40 + d] = yv[d] - m - logf(se);
    }
}

// ---------------------------------------------------------------------------
extern "C" void kernel_launch(void* const* d_in, const int* in_sizes, int n_in,
                              void* d_out, int out_size, void* d_ws, size_t ws_size,
                              hipStream_t stream)
{
    const float* x      = (const float*)d_in[0];
    const float* adj    = (const float*)d_in[1];
    const float* lin1W  = (const float*)d_in[2];
    const float* inproj = (const float*)d_in[3];
    const float* convw  = (const float*)d_in[4];
    const float* convb  = (const float*)d_in[5];
    const float* dtbias = (const float*)d_in[6];
    const float* m2Alog = (const float*)d_in[7];
    const float* m2D    = (const float*)d_in[8];
    const float* normw  = (const float*)d_in[9];
    const float* outprj = (const float*)d_in[10];
    const float* xprojW = (const float*)d_in[11];
    const float* dtprjW = (const float*)d_in[12];
    const float* bAlog  = (const float*)d_in[13];
    const float* bD     = (const float*)d_in[14];
    const float* boutW  = (const float*)d_in[15];
    const float* bn1g   = (const float*)d_in[16];
    const float* bn1b   = (const float*)d_in[17];
    const float* bn2g   = (const float*)d_in[18];
    const float* bn2b   = (const float*)d_in[19];
    const float* lin2W  = (const float*)d_in[20];
    float* out = (float*)d_out;
    float* ws  = (float*)d_ws;

    // fp32 buffers
    float* X     = ws + 0;         // 2048x256
    float* Z     = ws + 524288;    // 2048x560
    float* xhf   = ws + 1802240;   // 2048x256
    float* Bf    = ws + 2326528;   // 2048x8
    float* Cf    = ws + 2342912;
    float* xhr   = ws + 2359296;
    float* Br    = ws + 2883584;
    float* Cr    = ws + 2899968;
    float* yf    = ws + 2916352;
    float* yr    = ws + 3440640;
    float* gout  = ws + 4489216;
    float* xdbl  = ws + 9207808;   // 16384x48
    float* lastl = ws + 9994240;   // 2048x256
    // scan scratch (dead before chain; chain's psum16 overlays same region)
    float* scr    = ws + 10518528;
    float* Ptbuf  = scr;               // 131072
    float* Acbuf  = scr + 131072;      // 2048
    float* Sloc   = scr + 133120;      // 131072
    float* Sstart = scr + 264192;      // 131072
    // chain split-K fp16 psum (overlays scan scratch region, temporally disjoint)
    _Float16* psum16 = (_Float16*)(ws + 10518528);  // 8x2048x256 halves
    // fp16 buffers
    _Float16* adj16h    = (_Float16*)(ws + 14712832);  // 2048x2048
    _Float16* fT16A     = (_Float16*)(ws + 16809984);  // 256x2048
    _Float16* WT16h     = (_Float16*)(ws + 17072128);  // boutW^T 256x256
    _Float16* x16       = (_Float16*)(ws + 17104896);  // 2048x512
    _Float16* lin1WT16  = (_Float16*)(ws + 17629184);  // 256x512
    _Float16* inprojT16 = (_Float16*)(ws + 17694720);  // 576x256
    _Float16* outprjT16 = (_Float16*)(ws + 17768448);  // 256x256
    _Float16* xprojT16  = (_Float16*)(ws + 17801216);  // 64x256
    _Float16* X16       = (_Float16*)(ws + 17809408);  // 2048x256
    _Float16* gsum16    = (_Float16*)(ws + 18071552);  // 2048x256
    _Float16* feats16a  = (_Float16*)(ws + 18333696);  // 16384x256
    (void)ws_size; (void)in_sizes; (void)n_in; (void)out_size;

    dim3 blk(256);
    // 1. one-shot conversions
    k_prep<<<dim3(6784), blk, 0, stream>>>(x, adj, lin1W, inproj, outprj, xprojW, boutW,
                                           x16, adj16h, lin1WT16, inprojT16, outprjT16,
                                           xprojT16, WT16h);
    // 2. X = x @ lin1_W  (fp32 + fp16 mirror)
    mm16<4><<<dim3(4, 16, 1), blk, 0, stream>>>(x16, 512, lin1WT16, 512, X, X16, nullptr, nullptr, 256, 256, 512);
    // 3. Z = X @ in_proj
    mm16<5><<<dim3(9, 16, 1), blk, 0, stream>>>(X16, 256, inprojT16, 256, Z, nullptr, nullptr, nullptr, 560, 560, 256);
    // 4. conv (both directions)
    k_conv<<<dim3(4096), dim3(320), 0, stream>>>(Z, convw, convb, xhf, Bf, Cf, xhr, Br, Cr);
    // 5. chunk-parallel bidirectional scan (dt/dA inline)
    k_scan_m2_p1<<<dim3(2048), dim3(64), 0, stream>>>(Z, dtbias, m2Alog, xhf, Bf, Cf, xhr, Br, Cr,
                                                      m2D, yf, yr, Ptbuf, Acbuf, Sloc);
    k_scan_m2_p2<<<dim3(64), dim3(64), 0, stream>>>(Acbuf, Sloc, Sstart);
    // 6. gate + RMS -> gsum16
    k_gate<<<dim3(2048), blk, 0, stream>>>(Z, yf, yr, Cf, Cr, Ptbuf, Sstart, normw, gsum16);
    // 7. gout = relu(gsum@out_proj)*0.9 + 0.1*X
    mm16<2><<<dim3(4, 16, 1), blk, 0, stream>>>(gsum16, 256, outprjT16, 256, gout, nullptr, X, nullptr, 256, 256, 256);
    // 8. feats16a[0] = xb (fp16 + fp16^T)
    k_xb_t16<<<dim3(512), blk, 0, stream>>>(X, bn1g, bn1b, feats16a, fT16A);
    // 9. GCN chain via fp16 MFMA split-K=8 (fp16 psum) + combine
    for (int i = 1; i < 8; ++i) {
        mm16<0><<<dim3(4, 16, 8), blk, 0, stream>>>(adj16h, 2048, fT16A, 2048, nullptr, psum16, nullptr, nullptr, 256, 256, 256);
        k_combine16<<<dim3(512), blk, 0, stream>>>(psum16, feats16a,
                                                   feats16a + (size_t)i * 524288, fT16A);
    }
    // 10. xdbl = relu(feats @ xproj_W)
    mm16<1><<<dim3(1, 128, 1), blk, 0, stream>>>(feats16a, 256, xprojT16, 256, xdbl, nullptr, nullptr, nullptr, 48, 48, 256);
    // 11. GCN scan -> y (fp16 in-place)
    k_scan_gcn<<<dim3(2048), blk, 0, stream>>>(xdbl, dtprjW, bAlog, bD, feats16a);
    // 12. all_out = relu(y @ outproj_W) remap + lastl
    mm16<3><<<dim3(4, 128, 1), blk, 0, stream>>>(feats16a, 256, WT16h, 256, out, nullptr, nullptr, lastl, 256, 256, 256);
    // 13. head
    k_head<<<dim3(2048), blk, 0, stream>>>(lastl, X, gout, bn2g, bn2b, lin2W, out + 4194304);
}